// Round 20
// baseline (947.543 us; speedup 1.0000x reference)
//
#include <hip/hip_runtime.h>
#include <stdint.h>

#define Bsz 256
#define Tt  128
#define INs 256
#define Hh  512

typedef __attribute__((ext_vector_type(8))) short short8;
typedef __attribute__((ext_vector_type(4))) float f32x4;

__device__ __forceinline__ unsigned short f2bf(float f) {
  union { float f; unsigned int u; } v; v.f = f;
  unsigned int u = v.u;
  u += 0x7FFFu + ((u >> 16) & 1u);   // round-to-nearest-even
  return (unsigned short)(u >> 16);
}
__device__ __forceinline__ float bf2f(unsigned short h) {
  union { unsigned int u; float f; } v; v.u = ((unsigned int)h) << 16;
  return v.f;
}
__device__ __forceinline__ float sigf(float x) { return 1.0f / (1.0f + expf(-x)); }

#define AL(P)    __hip_atomic_load((P), __ATOMIC_RELAXED, __HIP_MEMORY_SCOPE_AGENT)
#define AS(P, V) __hip_atomic_store((P), (V), __ATOMIC_RELAXED, __HIP_MEMORY_SCOPE_AGENT)

union Q2S { unsigned long long q[2]; short8 s; };

// ---- ws layout (bytes) ---- (r15-identical)
#define WS_F0 0
#define WS_F1 32768
#define WS_H0 65536                               // 4 slots x 256 KB (block layout)
#define WS_H1 (WS_H0 + 4 * Bsz * Hh * 2)          // 2 slots x 256 KB
#define WS_ZERO_BYTES (WS_H1 + 2 * Bsz * Hh * 2)  // 1638400

#define W_BYTES   131072
#define HX_OFF    (W_BYTES + 64 * 4 + 48 * 4)     // wave-private h scratch
#define DYN_SHMEM (HX_OFF + 4 * 512)

// poll this plane's 32 flags; sched_barrier(0) at exit pins program order so
// the compiler can NOT hoist subsequent relaxed data loads above the poll.
#define POLLW(BASE, TGT)                                                        \
  if ((TGT) > 0) {                                                              \
    const int* fp_ = (BASE) + ((lane & 31) << 4);                               \
    int v_ = AL(fp_);                                                           \
    while (__ballot(v_ >= (TGT)) != ~0ull) {                                    \
      __builtin_amdgcn_s_sleep(10);                                             \
      v_ = AL(fp_);                                                             \
    }                                                                           \
    __builtin_amdgcn_sched_barrier(0);                                          \
  }

// load ksteps [S0,S1) of one 16-row A plane into PQ slots [2*S0, 2*S1)
#define H_LOAD_RANGE(PQ, PA, S0, S1)                                            \
  _Pragma("unroll")                                                             \
  for (int s = (S0); s < (S1); ++s) {                                           \
    const unsigned long long* qa =                                              \
        (const unsigned long long*)((PA) + s * 2048);                           \
    PQ[s * 2] = AL(qa); PQ[s * 2 + 1] = AL(qa + 1);                             \
  }

// MFMA ksteps [S0,S1) from PQ against LDS weights at kstep base KB
#define H_MFMA_RANGE(PQ, KB, S0, S1)                                            \
  _Pragma("unroll")                                                             \
  for (int ks = (S0); ks < (S1); ++ks) {                                        \
    Q2S u_; u_.q[0] = PQ[ks * 2]; u_.q[1] = PQ[ks * 2 + 1];                     \
    _Pragma("unroll")                                                           \
    for (int c4 = 0; c4 < 4; ++c4) {                                            \
      short8 b = *(const short8*)(smem + (((ks + (KB)) * 4 + c4) * 64 + lane) * 16); \
      acc[c4] = __builtin_amdgcn_mfma_f32_16x16x32_bf16(u_.s, b, acc[c4], 0, 0, 0);  \
    }                                                                           \
  }

// x-part MFMA for ksteps [S0,S1): plain cached loads, fp32 -> bf16 on the fly
#define X_MFMA_RANGE(XP, S0, S1)                                                \
  _Pragma("unroll")                                                             \
  for (int ks = (S0); ks < (S1); ++ks) {                                        \
    const float* s0 = (XP) + ks * 32;                                           \
    short8 a_;                                                                  \
    _Pragma("unroll")                                                           \
    for (int j = 0; j < 8; ++j) a_[j] = (short)f2bf(s0[j]);                     \
    _Pragma("unroll")                                                           \
    for (int c4 = 0; c4 < 4; ++c4) {                                            \
      short8 b = *(const short8*)(smem + ((ks * 4 + c4) * 64 + lane) * 16);     \
      acc[c4] = __builtin_amdgcn_mfma_f32_16x16x32_bf16(a_, b, acc[c4], 0, 0, 0);    \
    }                                                                           \
  }

// in-register peephole elementwise; h routed through wave-private LDS tile
// so each lane emits ONE dense 8B UC store (wave = contiguous 512B block).
#define ELEMWISE(HDST)                                                          \
  {                                                                             \
    const int jj = lane & 15;                                                   \
    unsigned short* hx = (unsigned short*)(smem + HX_OFF) + (wave << 8);        \
    _Pragma("unroll")                                                           \
    for (int v = 0; v < 4; ++v) {                                               \
      const int r = ((lane >> 4) << 2) + v;                                     \
      float gi = acc[0][v] + bxl[jj];                                           \
      float gf = acc[1][v] + bxl[16 + jj];                                      \
      float gg = acc[2][v] + bxl[32 + jj];                                      \
      float go = acc[3][v] + bxl[48 + jj];                                      \
      float co = cr[v];                                                         \
      float iv = sigf(gi + co * wcl[jj]);                                       \
      float fv = sigf(gf + co * wcl[16 + jj]);                                  \
      float gv = tanhf(gg);                                                     \
      float cn = fv * co + iv * gv;                                             \
      float ov = sigf(go + cn * wcl[32 + jj]);                                  \
      cr[v] = cn;                                                               \
      hx[r * 16 + jj] = f2bf(ov * tanhf(cn));                                   \
    }                                                                           \
    asm volatile("s_waitcnt lgkmcnt(0)" ::: "memory");                          \
    __builtin_amdgcn_sched_barrier(0);                                          \
    const unsigned long long hq =                                               \
        *(const unsigned long long*)(hx + ((lane >> 2) << 4) + ((lane & 3) << 2)); \
    AS((unsigned long long*)((HDST) + (size_t)g * 32768 + (size_t)cb * 1024     \
                             + (size_t)((wave << 4) + (lane >> 2)) * 16         \
                             + ((lane & 3) << 2)),                              \
       hq);                                                                     \
  }

#define VM0() asm volatile("s_waitcnt vmcnt(0)" ::: "memory")

extern "C" __global__ void __launch_bounds__(256)
lstm_fused(const float* __restrict__ x,
           const float* __restrict__ Wx0, const float* __restrict__ bx0,
           const float* __restrict__ Wh0, const float* __restrict__ Wc0,
           const float* __restrict__ Wx1, const float* __restrict__ bx1,
           const float* __restrict__ Wh1, const float* __restrict__ Wc1,
           const float* __restrict__ Wfc, const float* __restrict__ bfc,
           float* __restrict__ out, unsigned char* __restrict__ ws)
{
  extern __shared__ char smem[];
  unsigned short* h0b = (unsigned short*)(ws + WS_H0);
  unsigned short* h1b = (unsigned short*)(ws + WS_H1);
  float* bxl = (float*)(smem + W_BYTES);
  float* wcl = bxl + 64;

  const int wg    = blockIdx.x;
  const int g     = wg >> 6;        // batch-row group (0..3), 64 rows each
  const int sub   = wg & 63;
  const int layer = sub >> 5;
  const int cb    = sub & 31;       // 16 hidden cols
  const int tid   = threadIdx.x;
  const int lane  = tid & 63;
  const int wave  = tid >> 6;       // wave-plane: rows g*64 + wave*16 .. +15
  const int j0    = cb << 4;

  // per-wave flag bases for this (group, plane)
  int* f0p = (int*)(ws + WS_F0) + (((g << 2) + wave) << 9);   // 32 flags x 16 ints
  int* f1p = (int*)(ws + WS_F1) + (((g << 2) + wave) << 9);
  int* myflag = (layer ? f1p : f0p) + (cb << 4);

  // ---- preload this WG's weight slice into LDS, bf16, fragment order ----
  {
    const int K   = layer ? 1024 : 768;
    const int k8s = K >> 3;
    const int ng  = 64 * k8s;
    for (int idx = tid; idx < ng; idx += 256) {
      const int nl = idx / k8s;
      const int k8 = idx - nl * k8s;
      const int k  = k8 << 3;
      const int nrow = (nl >> 4) * Hh + j0 + (nl & 15);
      const float* src;
      if (!layer) src = (k < INs) ? (Wx0 + (size_t)nrow * INs + k)
                                  : (Wh0 + (size_t)nrow * Hh + (k - INs));
      else        src = (k < Hh)  ? (Wx1 + (size_t)nrow * Hh + k)
                                  : (Wh1 + (size_t)nrow * Hh + (k - Hh));
      short8 v;
      #pragma unroll
      for (int j = 0; j < 8; ++j) v[j] = (short)f2bf(src[j]);
      const int slot = ((k8 >> 2) * 4 + (nl >> 4)) * 64 + ((k8 & 3) * 16 + (nl & 15));
      *(short8*)(smem + slot * 16) = v;
    }
  }
  {
    const float* bx = layer ? bx1 : bx0;
    const float* Wc = layer ? Wc1 : Wc0;
    if (tid < 64) bxl[tid] = bx[(tid >> 4) * Hh + j0 + (tid & 15)];
    if (tid < 48) wcl[tid] = Wc[(tid >> 4) * Hh + j0 + (tid & 15)];
  }
  __syncthreads();   // weights ready (only barrier before epilogue)

  // ---- wave tile: 16 rows x 64 gate-cols ----
  const int lr   = (wave << 4) + (lane & 15);   // local row 0..63
  const int koff = (lane >> 4) << 3;            // shorts (x addressing)
  const int bg   = (g << 6) + lr;               // global batch row (x only)

  // per-lane base offset into block-layout h (u16): [g][cb-parity][row][col]
  const size_t hoff = (size_t)g * 32768 + (size_t)((lane >> 5) & 1) * 1024
                    + (size_t)lr * 16 + (size_t)((lane >> 4) & 1) * 8;

  float cr[4] = {0.f, 0.f, 0.f, 0.f};
  const f32x4 zz = {0.f, 0.f, 0.f, 0.f};

  if (!layer) {
    // =============== LAYER 0 (split x-part: ks0-3 fills propagate window,
    //                 ks4-7 hides the h0-load RTT) ===============
    for (int t = 0; t < Tt; ++t) {
      f32x4 acc[4] = {zz, zz, zz, zz};
      const float* xp = x + ((size_t)bg * Tt + t) * INs + koff;
      X_MFMA_RANGE(xp, 0, 4)           // peer-independent window filler
      POLLW(f0p, t)        // plane peers' h0[t-1] written
      const unsigned short* hp = h0b + (size_t)((t + 3) & 3) * (Bsz * Hh) + hoff;
      unsigned long long pq[32];
      H_LOAD_RANGE(pq, hp, 0, 16)      // h0 loads issued...
      X_MFMA_RANGE(xp, 4, 8)           // ...their RTT hides under x ks4-7
      H_MFMA_RANGE(pq, 8, 0, 16)       // h0[t-1] @ Wh0
      POLLW(f1p, t - 3)    // L1 plane consumed h0[t-4] -> slot t&3 reusable
      ELEMWISE(h0b + (size_t)(t & 3) * (Bsz * Hh))
      VM0();               // this wave's h store visible at IF
      if (lane == 0) AS(myflag, t + 1);
    }
  } else {
    // =============== LAYER 1 (r19's interleave, single pq) ==========
    for (int u = 0; u < Tt; ++u) {
      f32x4 acc[4] = {zz, zz, zz, zz};
      POLLW(f0p, u + 1)    // L0 leads: ~instant
      const unsigned short* ap = h0b + (size_t)(u & 3) * (Bsz * Hh) + hoff;
      unsigned long long pq[32];
      H_LOAD_RANGE(pq, ap, 0, 16)      // h0[u] loads
      H_MFMA_RANGE(pq, 0, 0, 8)        // h0 ks 0-7 (consumes pq[0..15])
      POLLW(f1p, u)        // peers' h1[u-1] visible
      const unsigned short* bp = h1b + (size_t)((u + 1) & 1) * (Bsz * Hh) + hoff;
      H_LOAD_RANGE(pq, bp, 0, 8)       // h1 ks 0-7 -> pq[0..15] (freed), fly...
      H_MFMA_RANGE(pq, 0, 8, 16)       // ...under h0 ks 8-15 (pq[16..31])
      H_LOAD_RANGE(pq, bp, 8, 16)      // h1 ks 8-15 -> pq[16..31] (freed)
      H_MFMA_RANGE(pq, 16, 0, 8)       // h1 ks 0-7
      H_MFMA_RANGE(pq, 16, 8, 16)      // h1 ks 8-15
      ELEMWISE(h1b + (size_t)(u & 1) * (Bsz * Hh))
      VM0();
      if (lane == 0) AS(myflag, u + 1);
    }
  }

  // ---- epilogue: wait for my output group's 128 L1 wave-flags ----
  {
    const int og = wg >> 6;
    const int* fb = (int*)(ws + WS_F1) + (og << 11);   // 128 flags x 16 ints
    const int* fa = fb + (lane << 4);
    const int* fc = fb + ((lane + 64) << 4);
    for (;;) {
      int va = AL(fa), vb = AL(fc);
      if (__ballot((va >= Tt) && (vb >= Tt)) == ~0ull) break;
      __builtin_amdgcn_s_sleep(10);
    }
  }
  __builtin_amdgcn_fence(__ATOMIC_ACQUIRE, "agent");
  __builtin_amdgcn_sched_barrier(0);

  // ---- final FC: out[wg][0..7] = h1_final[wg] @ Wfc^T + bfc ----
  // block layout: row (wg&63) of group (wg>>6), cb = ksl
  const unsigned short* hf = h1b + (size_t)(Bsz * Hh);  // slot 1 holds h1[127]
  float* red = (float*)smem;
  const int cc = tid & 7, ksl = tid >> 3;
  const unsigned short* hr = hf + (size_t)(wg >> 6) * 32768
                                + (size_t)ksl * 1024 + (size_t)(wg & 63) * 16;
  const float* wr = Wfc + (size_t)cc * Hh + ksl * 16;
  float s = 0.f;
  #pragma unroll
  for (int k = 0; k < 16; ++k) s += bf2f(hr[k]) * wr[k];
  __syncthreads();           // all waves done with weight-smem before reuse
  red[tid] = s;
  __syncthreads();
  if (tid < 8) {
    float a = bfc[tid];
    #pragma unroll
    for (int i = 0; i < 32; ++i) a += red[i * 8 + tid];
    out[wg * 8 + tid] = a;
  }
}

extern "C" void kernel_launch(void* const* d_in, const int* in_sizes, int n_in,
                              void* d_out, int out_size, void* d_ws, size_t ws_size,
                              hipStream_t stream) {
  if (ws_size < (size_t)WS_ZERO_BYTES) return;

  const float* x   = (const float*)d_in[0];
  const float* Wx0 = (const float*)d_in[1];
  const float* bx0 = (const float*)d_in[2];
  const float* Wh0 = (const float*)d_in[3];
  const float* Wc0 = (const float*)d_in[4];
  const float* Wx1 = (const float*)d_in[5];
  const float* bx1 = (const float*)d_in[6];
  const float* Wh1 = (const float*)d_in[7];
  const float* Wc1 = (const float*)d_in[8];
  const float* Wfc = (const float*)d_in[9];
  const float* bfc = (const float*)d_in[10];
  float* out = (float*)d_out;
  unsigned char* ws = (unsigned char*)d_ws;

  (void)hipMemsetAsync(d_ws, 0, WS_ZERO_BYTES, stream);
  (void)hipFuncSetAttribute(reinterpret_cast<const void*>(lstm_fused),
                            hipFuncAttributeMaxDynamicSharedMemorySize, DYN_SHMEM);
  void* args[] = {&x, &Wx0, &bx0, &Wh0, &Wc0, &Wx1, &bx1, &Wh1, &Wc1, &Wfc, &bfc, &out, &ws};
  (void)hipLaunchCooperativeKernel((void*)lstm_fused, dim3(256), dim3(256), args,
                                   (unsigned int)DYN_SHMEM, stream);
}

// Round 21
// 767.842 us; speedup vs baseline: 1.2340x; 1.2340x over previous
//
#include <hip/hip_runtime.h>
#include <stdint.h>
#include <math.h>

#define Bsz 256
#define Tt  128
#define INs 256
#define Hh  512

typedef __attribute__((ext_vector_type(8))) short short8;
typedef __attribute__((ext_vector_type(4))) float f32x4;

__device__ __forceinline__ unsigned short f2bf(float f) {
  union { float f; unsigned int u; } v; v.f = f;
  unsigned int u = v.u;
  u += 0x7FFFu + ((u >> 16) & 1u);   // round-to-nearest-even
  return (unsigned short)(u >> 16);
}
__device__ __forceinline__ float bf2f(unsigned short h) {
  union { unsigned int u; float f; } v; v.u = ((unsigned int)h) << 16;
  return v.f;
}
// fast sigmoid/tanh via native v_exp_f32 (__expf); args here are small/bounded
__device__ __forceinline__ float sigf(float x) {
  return 1.0f / (1.0f + __expf(-x));
}
__device__ __forceinline__ float tanhfast(float x) {
  float ax = fabsf(x);
  float t = 1.0f - 2.0f / (__expf(2.0f * ax) + 1.0f);
  return copysignf(t, x);
}

#define AL(P)    __hip_atomic_load((P), __ATOMIC_RELAXED, __HIP_MEMORY_SCOPE_AGENT)
#define AS(P, V) __hip_atomic_store((P), (V), __ATOMIC_RELAXED, __HIP_MEMORY_SCOPE_AGENT)

union Q2S { unsigned long long q[2]; short8 s; };

// ---- ws layout (bytes) ---- (r15-identical)
#define WS_F0 0
#define WS_F1 32768
#define WS_H0 65536                               // 4 slots x 256 KB (block layout)
#define WS_H1 (WS_H0 + 4 * Bsz * Hh * 2)          // 2 slots x 256 KB
#define WS_ZERO_BYTES (WS_H1 + 2 * Bsz * Hh * 2)  // 1638400

#define W_BYTES   131072
#define HX_OFF    (W_BYTES + 64 * 4 + 48 * 4)     // wave-private h scratch
#define DYN_SHMEM (HX_OFF + 4 * 512)

// poll this plane's 32 flags; sched_barrier(0) at exit pins program order so
// the compiler can NOT hoist subsequent relaxed data loads above the poll.
#define POLLW(BASE, TGT)                                                        \
  if ((TGT) > 0) {                                                              \
    const int* fp_ = (BASE) + ((lane & 31) << 4);                               \
    int v_ = AL(fp_);                                                           \
    while (__ballot(v_ >= (TGT)) != ~0ull) {                                    \
      __builtin_amdgcn_s_sleep(4);                                              \
      v_ = AL(fp_);                                                             \
    }                                                                           \
    __builtin_amdgcn_sched_barrier(0);                                          \
  }

// load ksteps [S0,S1) of one 16-row A plane into PQ slots [2*S0, 2*S1)
#define H_LOAD_RANGE(PQ, PA, S0, S1)                                            \
  _Pragma("unroll")                                                             \
  for (int s = (S0); s < (S1); ++s) {                                           \
    const unsigned long long* qa =                                              \
        (const unsigned long long*)((PA) + s * 2048);                           \
    PQ[s * 2] = AL(qa); PQ[s * 2 + 1] = AL(qa + 1);                             \
  }

// MFMA ksteps [S0,S1) from PQ against LDS weights at kstep base KB
#define H_MFMA_RANGE(PQ, KB, S0, S1)                                            \
  _Pragma("unroll")                                                             \
  for (int ks = (S0); ks < (S1); ++ks) {                                        \
    Q2S u_; u_.q[0] = PQ[ks * 2]; u_.q[1] = PQ[ks * 2 + 1];                     \
    _Pragma("unroll")                                                           \
    for (int c4 = 0; c4 < 4; ++c4) {                                            \
      short8 b = *(const short8*)(smem + (((ks + (KB)) * 4 + c4) * 64 + lane) * 16); \
      acc[c4] = __builtin_amdgcn_mfma_f32_16x16x32_bf16(u_.s, b, acc[c4], 0, 0, 0);  \
    }                                                                           \
  }

// in-register peephole elementwise; h routed through wave-private LDS tile
// so each lane emits ONE dense 8B UC store (wave = contiguous 512B block).
#define ELEMWISE(HDST)                                                          \
  {                                                                             \
    const int jj = lane & 15;                                                   \
    unsigned short* hx = (unsigned short*)(smem + HX_OFF) + (wave << 8);        \
    _Pragma("unroll")                                                           \
    for (int v = 0; v < 4; ++v) {                                               \
      const int r = ((lane >> 4) << 2) + v;                                     \
      float gi = acc[0][v] + bxl[jj];                                           \
      float gf = acc[1][v] + bxl[16 + jj];                                      \
      float gg = acc[2][v] + bxl[32 + jj];                                      \
      float go = acc[3][v] + bxl[48 + jj];                                      \
      float co = cr[v];                                                         \
      float iv = sigf(gi + co * wcl[jj]);                                       \
      float fv = sigf(gf + co * wcl[16 + jj]);                                  \
      float gv = tanhfast(gg);                                                  \
      float cn = fv * co + iv * gv;                                             \
      float ov = sigf(go + cn * wcl[32 + jj]);                                  \
      cr[v] = cn;                                                               \
      hx[r * 16 + jj] = f2bf(ov * tanhfast(cn));                                \
    }                                                                           \
    asm volatile("s_waitcnt lgkmcnt(0)" ::: "memory");                          \
    __builtin_amdgcn_sched_barrier(0);                                          \
    const unsigned long long hq =                                               \
        *(const unsigned long long*)(hx + ((lane >> 2) << 4) + ((lane & 3) << 2)); \
    AS((unsigned long long*)((HDST) + (size_t)g * 32768 + (size_t)cb * 1024     \
                             + (size_t)((wave << 4) + (lane >> 2)) * 16         \
                             + ((lane & 3) << 2)),                              \
       hq);                                                                     \
  }

#define VM0() asm volatile("s_waitcnt vmcnt(0)" ::: "memory")

extern "C" __global__ void __launch_bounds__(256)
lstm_fused(const float* __restrict__ x,
           const float* __restrict__ Wx0, const float* __restrict__ bx0,
           const float* __restrict__ Wh0, const float* __restrict__ Wc0,
           const float* __restrict__ Wx1, const float* __restrict__ bx1,
           const float* __restrict__ Wh1, const float* __restrict__ Wc1,
           const float* __restrict__ Wfc, const float* __restrict__ bfc,
           float* __restrict__ out, unsigned char* __restrict__ ws)
{
  extern __shared__ char smem[];
  unsigned short* h0b = (unsigned short*)(ws + WS_H0);
  unsigned short* h1b = (unsigned short*)(ws + WS_H1);
  float* bxl = (float*)(smem + W_BYTES);
  float* wcl = bxl + 64;

  const int wg    = blockIdx.x;
  const int g     = wg >> 6;        // batch-row group (0..3), 64 rows each
  const int sub   = wg & 63;
  const int layer = sub >> 5;
  const int cb    = sub & 31;       // 16 hidden cols
  const int tid   = threadIdx.x;
  const int lane  = tid & 63;
  const int wave  = tid >> 6;       // wave-plane: rows g*64 + wave*16 .. +15
  const int j0    = cb << 4;

  // per-wave flag bases for this (group, plane)
  int* f0p = (int*)(ws + WS_F0) + (((g << 2) + wave) << 9);   // 32 flags x 16 ints
  int* f1p = (int*)(ws + WS_F1) + (((g << 2) + wave) << 9);
  int* myflag = (layer ? f1p : f0p) + (cb << 4);

  // ---- preload this WG's weight slice into LDS, bf16, fragment order ----
  {
    const int K   = layer ? 1024 : 768;
    const int k8s = K >> 3;
    const int ng  = 64 * k8s;
    for (int idx = tid; idx < ng; idx += 256) {
      const int nl = idx / k8s;
      const int k8 = idx - nl * k8s;
      const int k  = k8 << 3;
      const int nrow = (nl >> 4) * Hh + j0 + (nl & 15);
      const float* src;
      if (!layer) src = (k < INs) ? (Wx0 + (size_t)nrow * INs + k)
                                  : (Wh0 + (size_t)nrow * Hh + (k - INs));
      else        src = (k < Hh)  ? (Wx1 + (size_t)nrow * Hh + k)
                                  : (Wh1 + (size_t)nrow * Hh + (k - Hh));
      short8 v;
      #pragma unroll
      for (int j = 0; j < 8; ++j) v[j] = (short)f2bf(src[j]);
      const int slot = ((k8 >> 2) * 4 + (nl >> 4)) * 64 + ((k8 & 3) * 16 + (nl & 15));
      *(short8*)(smem + slot * 16) = v;
    }
  }
  {
    const float* bx = layer ? bx1 : bx0;
    const float* Wc = layer ? Wc1 : Wc0;
    if (tid < 64) bxl[tid] = bx[(tid >> 4) * Hh + j0 + (tid & 15)];
    if (tid < 48) wcl[tid] = Wc[(tid >> 4) * Hh + j0 + (tid & 15)];
  }
  __syncthreads();   // weights ready (only barrier before epilogue)

  // ---- wave tile: 16 rows x 64 gate-cols ----
  const int lr   = (wave << 4) + (lane & 15);   // local row 0..63
  const int koff = (lane >> 4) << 3;            // shorts (x addressing)
  const int bg   = (g << 6) + lr;               // global batch row (x only)

  // per-lane base offset into block-layout h (u16): [g][cb-parity][row][col]
  const size_t hoff = (size_t)g * 32768 + (size_t)((lane >> 5) & 1) * 1024
                    + (size_t)lr * 16 + (size_t)((lane >> 4) & 1) * 8;

  float cr[4] = {0.f, 0.f, 0.f, 0.f};
  const f32x4 zz = {0.f, 0.f, 0.f, 0.f};

  if (!layer) {
    // =============== LAYER 0 (r15/r19 ordering: full x-part fills window) ===
    for (int t = 0; t < Tt; ++t) {
      f32x4 acc[4] = {zz, zz, zz, zz};
      const float* xp = x + ((size_t)bg * Tt + t) * INs + koff;
      #pragma unroll 2
      for (int ks = 0; ks < 8; ++ks) {
        const float* s0 = xp + ks * 32;
        short8 a;
        #pragma unroll
        for (int j = 0; j < 8; ++j) a[j] = (short)f2bf(s0[j]);
        #pragma unroll
        for (int c4 = 0; c4 < 4; ++c4) {
          short8 b = *(const short8*)(smem + ((ks * 4 + c4) * 64 + lane) * 16);
          acc[c4] = __builtin_amdgcn_mfma_f32_16x16x32_bf16(a, b, acc[c4], 0, 0, 0);
        }
      }
      POLLW(f0p, t)        // plane peers' h0[t-1] written
      POLLW(f1p, t - 3)    // L1 plane consumed h0[t-4] -> slot t&3 reusable
      const unsigned short* hp = h0b + (size_t)((t + 3) & 3) * (Bsz * Hh) + hoff;
      {
        unsigned long long pq[32];
        H_LOAD_RANGE(pq, hp, 0, 16)
        H_MFMA_RANGE(pq, 8, 0, 16)     // h0[t-1] @ Wh0
      }
      ELEMWISE(h0b + (size_t)(t & 3) * (Bsz * Hh))
      VM0();               // this wave's h store visible at IF
      if (lane == 0) AS(myflag, t + 1);
    }
  } else {
    // =============== LAYER 1 (r19's interleave, single pq) ==========
    for (int u = 0; u < Tt; ++u) {
      f32x4 acc[4] = {zz, zz, zz, zz};
      POLLW(f0p, u + 1)    // L0 leads: ~instant
      const unsigned short* ap = h0b + (size_t)(u & 3) * (Bsz * Hh) + hoff;
      unsigned long long pq[32];
      H_LOAD_RANGE(pq, ap, 0, 16)      // h0[u] loads
      H_MFMA_RANGE(pq, 0, 0, 8)        // h0 ks 0-7 (consumes pq[0..15])
      POLLW(f1p, u)        // peers' h1[u-1] visible
      const unsigned short* bp = h1b + (size_t)((u + 1) & 1) * (Bsz * Hh) + hoff;
      H_LOAD_RANGE(pq, bp, 0, 8)       // h1 ks 0-7 -> pq[0..15] (freed), fly...
      H_MFMA_RANGE(pq, 0, 8, 16)       // ...under h0 ks 8-15 (pq[16..31])
      H_LOAD_RANGE(pq, bp, 8, 16)      // h1 ks 8-15 -> pq[16..31] (freed)
      H_MFMA_RANGE(pq, 16, 0, 8)       // h1 ks 0-7
      H_MFMA_RANGE(pq, 16, 8, 16)      // h1 ks 8-15
      ELEMWISE(h1b + (size_t)(u & 1) * (Bsz * Hh))
      VM0();
      if (lane == 0) AS(myflag, u + 1);
    }
  }

  // ---- epilogue: wait for my output group's 128 L1 wave-flags ----
  {
    const int og = wg >> 6;
    const int* fb = (int*)(ws + WS_F1) + (og << 11);   // 128 flags x 16 ints
    const int* fa = fb + (lane << 4);
    const int* fc = fb + ((lane + 64) << 4);
    for (;;) {
      int va = AL(fa), vb = AL(fc);
      if (__ballot((va >= Tt) && (vb >= Tt)) == ~0ull) break;
      __builtin_amdgcn_s_sleep(4);
    }
  }
  __builtin_amdgcn_fence(__ATOMIC_ACQUIRE, "agent");
  __builtin_amdgcn_sched_barrier(0);

  // ---- final FC: out[wg][0..7] = h1_final[wg] @ Wfc^T + bfc ----
  // block layout: row (wg&63) of group (wg>>6), cb = ksl
  const unsigned short* hf = h1b + (size_t)(Bsz * Hh);  // slot 1 holds h1[127]
  float* red = (float*)smem;
  const int cc = tid & 7, ksl = tid >> 3;
  const unsigned short* hr = hf + (size_t)(wg >> 6) * 32768
                                + (size_t)ksl * 1024 + (size_t)(wg & 63) * 16;
  const float* wr = Wfc + (size_t)cc * Hh + ksl * 16;
  float s = 0.f;
  #pragma unroll
  for (int k = 0; k < 16; ++k) s += bf2f(hr[k]) * wr[k];
  __syncthreads();           // all waves done with weight-smem before reuse
  red[tid] = s;
  __syncthreads();
  if (tid < 8) {
    float a = bfc[tid];
    #pragma unroll
    for (int i = 0; i < 32; ++i) a += red[i * 8 + tid];
    out[wg * 8 + tid] = a;
  }
}

extern "C" void kernel_launch(void* const* d_in, const int* in_sizes, int n_in,
                              void* d_out, int out_size, void* d_ws, size_t ws_size,
                              hipStream_t stream) {
  if (ws_size < (size_t)WS_ZERO_BYTES) return;

  const float* x   = (const float*)d_in[0];
  const float* Wx0 = (const float*)d_in[1];
  const float* bx0 = (const float*)d_in[2];
  const float* Wh0 = (const float*)d_in[3];
  const float* Wc0 = (const float*)d_in[4];
  const float* Wx1 = (const float*)d_in[5];
  const float* bx1 = (const float*)d_in[6];
  const float* Wh1 = (const float*)d_in[7];
  const float* Wc1 = (const float*)d_in[8];
  const float* Wfc = (const float*)d_in[9];
  const float* bfc = (const float*)d_in[10];
  float* out = (float*)d_out;
  unsigned char* ws = (unsigned char*)d_ws;

  (void)hipMemsetAsync(d_ws, 0, WS_ZERO_BYTES, stream);
  (void)hipFuncSetAttribute(reinterpret_cast<const void*>(lstm_fused),
                            hipFuncAttributeMaxDynamicSharedMemorySize, DYN_SHMEM);
  void* args[] = {&x, &Wx0, &bx0, &Wh0, &Wc0, &Wx1, &bx1, &Wh1, &Wc1, &Wfc, &bfc, &out, &ws};
  (void)hipLaunchCooperativeKernel((void*)lstm_fused, dim3(256), dim3(256), args,
                                   (unsigned int)DYN_SHMEM, stream);
}